// Round 1
// baseline (15452.725 us; speedup 1.0000x reference)
//
#include <hip/hip_runtime.h>
#include <hip/hip_bf16.h>
#include <math.h>

#define N_NODES 200000
#define N_EDGES 5000000
#define NFEAT 16
#define DIM 10
#define NGRAPH 1000

// ---------------- edge scatter: conv1 (16 features) ----------------
__global__ void scatter16(const float* __restrict__ x,
                          const int* __restrict__ src,
                          const int* __restrict__ dst,
                          float* __restrict__ agg) {
    int e = blockIdx.x * blockDim.x + threadIdx.x;
    if (e >= N_EDGES) return;
    int s = src[e];
    int d = dst[e];
    const float4* xr = reinterpret_cast<const float4*>(x + (size_t)s * NFEAT);
    float* a = agg + (size_t)d * NFEAT;
#pragma unroll
    for (int q = 0; q < 4; q++) {
        float4 v = xr[q];
        atomicAdd(a + q * 4 + 0, v.x);
        atomicAdd(a + q * 4 + 1, v.y);
        atomicAdd(a + q * 4 + 2, v.z);
        atomicAdd(a + q * 4 + 3, v.w);
    }
}

// ---------------- edge scatter: conv2..5 (10 features) ----------------
__global__ void scatter10(const float* __restrict__ h,
                          const int* __restrict__ src,
                          const int* __restrict__ dst,
                          float* __restrict__ agg) {
    int e = blockIdx.x * blockDim.x + threadIdx.x;
    if (e >= N_EDGES) return;
    int s = src[e];
    int d = dst[e];
    const float* hr = h + (size_t)s * DIM;
    float* a = agg + (size_t)d * DIM;
#pragma unroll
    for (int j = 0; j < DIM; j++) {
        atomicAdd(a + j, hr[j]);
    }
}

// ---------------- node kernel layer 1: z = x+agg (16) -> MLP 16->10->10, relu; pool ----------------
__global__ void node1(const float* __restrict__ x,
                      const float* __restrict__ agg,
                      const float* __restrict__ w1,   // [16][10]
                      const float* __restrict__ b1,   // [10]
                      const float* __restrict__ w2,   // [10][10]
                      const float* __restrict__ b2,   // [10]
                      const int* __restrict__ batch,
                      float* __restrict__ hout,       // [N][10]
                      float* __restrict__ pooled,     // [NGRAPH][10] (layer 0 slice)
                      float* __restrict__ counts) {
    int i = blockIdx.x * blockDim.x + threadIdx.x;
    if (i >= N_NODES) return;
    float z[NFEAT];
#pragma unroll
    for (int f = 0; f < NFEAT; f++) z[f] = x[(size_t)i * NFEAT + f] + agg[(size_t)i * NFEAT + f];
    float t[DIM];
#pragma unroll
    for (int j = 0; j < DIM; j++) {
        float s = b1[j];
#pragma unroll
        for (int f = 0; f < NFEAT; f++) s += z[f] * w1[f * DIM + j];
        t[j] = s > 0.f ? s : 0.f;
    }
    int g = batch[i];
#pragma unroll
    for (int j = 0; j < DIM; j++) {
        float s = b2[j];
#pragma unroll
        for (int f = 0; f < DIM; f++) s += t[f] * w2[f * DIM + j];
        s = s > 0.f ? s : 0.f;   // outer relu: x1 = relu(conv(...))
        hout[(size_t)i * DIM + j] = s;
        atomicAdd(&pooled[(size_t)g * DIM + j], s);
    }
    atomicAdd(&counts[g], 1.0f);
}

// ---------------- node kernel layers 2..5: z = h+agg (10) -> MLP 10->10->10, relu; pool ----------------
__global__ void node2(const float* __restrict__ agg,
                      const float* __restrict__ w1,   // [10][10]
                      const float* __restrict__ b1,
                      const float* __restrict__ w2,
                      const float* __restrict__ b2,
                      const int* __restrict__ batch,
                      float* __restrict__ h,          // in/out [N][10]
                      float* __restrict__ pooled) {   // layer slice [NGRAPH][10]
    int i = blockIdx.x * blockDim.x + threadIdx.x;
    if (i >= N_NODES) return;
    float z[DIM];
#pragma unroll
    for (int f = 0; f < DIM; f++) z[f] = h[(size_t)i * DIM + f] + agg[(size_t)i * DIM + f];
    float t[DIM];
#pragma unroll
    for (int j = 0; j < DIM; j++) {
        float s = b1[j];
#pragma unroll
        for (int f = 0; f < DIM; f++) s += z[f] * w1[f * DIM + j];
        t[j] = s > 0.f ? s : 0.f;
    }
    int g = batch[i];
#pragma unroll
    for (int j = 0; j < DIM; j++) {
        float s = b2[j];
#pragma unroll
        for (int f = 0; f < DIM; f++) s += t[f] * w2[f * DIM + j];
        s = s > 0.f ? s : 0.f;
        h[(size_t)i * DIM + j] = s;
        atomicAdd(&pooled[(size_t)g * DIM + j], s);
    }
}

// ---------------- final: out[g] = sigmoid(sum_l dot(pooled[l][g]/max(c,1), lw[l])) ----------------
__global__ void finalk(const float* __restrict__ pooled,  // [5][NGRAPH][10]
                       const float* __restrict__ counts,  // [NGRAPH]
                       const float* __restrict__ lw,      // [5][10]
                       float* __restrict__ out) {
    int g = blockIdx.x * blockDim.x + threadIdx.x;
    if (g >= NGRAPH) return;
    float c = counts[g];
    float inv = 1.0f / (c > 1.0f ? c : 1.0f);
    float s = 0.f;
#pragma unroll
    for (int l = 0; l < 5; l++) {
        float d = 0.f;
#pragma unroll
        for (int j = 0; j < DIM; j++)
            d += pooled[(size_t)l * NGRAPH * DIM + (size_t)g * DIM + j] * lw[l * DIM + j];
        s += d * inv;
    }
    out[g] = 1.0f / (1.0f + expf(-s));
}

extern "C" void kernel_launch(void* const* d_in, const int* in_sizes, int n_in,
                              void* d_out, int out_size, void* d_ws, size_t ws_size,
                              hipStream_t stream) {
    const float* x        = (const float*)d_in[0];
    const int*   ei       = (const int*)d_in[1];
    const int*   batch    = (const int*)d_in[2];
    const float* w1_1     = (const float*)d_in[3];
    const float* b1_1     = (const float*)d_in[4];
    const float* w2_1     = (const float*)d_in[5];
    const float* b2_1     = (const float*)d_in[6];
    const float* ws1      = (const float*)d_in[7];   // [4][10][10]
    const float* bs1      = (const float*)d_in[8];   // [4][10]
    const float* ws2      = (const float*)d_in[9];   // [4][10][10]
    const float* bs2      = (const float*)d_in[10];  // [4][10]
    const float* lw       = (const float*)d_in[11];  // [5][10]
    float* out = (float*)d_out;

    const int* src = ei;
    const int* dst = ei + N_EDGES;

    // workspace layout (floats)
    float* wsf    = (float*)d_ws;
    float* agg    = wsf;                                   // [N][16] (reused as [N][10])
    float* h      = agg + (size_t)N_NODES * NFEAT;         // [N][10]
    float* pooled = h + (size_t)N_NODES * DIM;             // [5][G][10]
    float* counts = pooled + (size_t)5 * NGRAPH * DIM;     // [G]

    const int TB = 256;
    int eblocks = (N_EDGES + TB - 1) / TB;
    int nblocks = (N_NODES + TB - 1) / TB;
    int gblocks = (NGRAPH + TB - 1) / TB;

    // zero pooled + counts (contiguous)
    hipMemsetAsync(pooled, 0, (size_t)(5 * NGRAPH * DIM + NGRAPH) * sizeof(float), stream);

    // ---- layer 1 ----
    hipMemsetAsync(agg, 0, (size_t)N_NODES * NFEAT * sizeof(float), stream);
    scatter16<<<eblocks, TB, 0, stream>>>(x, src, dst, agg);
    node1<<<nblocks, TB, 0, stream>>>(x, agg, w1_1, b1_1, w2_1, b2_1, batch,
                                      h, pooled, counts);

    // ---- layers 2..5 ----
    for (int l = 0; l < 4; l++) {
        hipMemsetAsync(agg, 0, (size_t)N_NODES * DIM * sizeof(float), stream);
        scatter10<<<eblocks, TB, 0, stream>>>(h, src, dst, agg);
        node2<<<nblocks, TB, 0, stream>>>(agg,
                                          ws1 + (size_t)l * DIM * DIM,
                                          bs1 + (size_t)l * DIM,
                                          ws2 + (size_t)l * DIM * DIM,
                                          bs2 + (size_t)l * DIM,
                                          batch, h,
                                          pooled + (size_t)(l + 1) * NGRAPH * DIM);
    }

    // ---- readout ----
    finalk<<<gblocks, TB, 0, stream>>>(pooled, counts, lw, out);
}

// Round 2
// 1434.762 us; speedup vs baseline: 10.7702x; 10.7702x over previous
//
#include <hip/hip_runtime.h>
#include <hip/hip_bf16.h>
#include <math.h>

#define N_NODES 200000
#define N_EDGES 5000000
#define NFEAT 16
#define DIM 10
#define NGRAPH 1000
#define NPB 16      // nodes per 256-thread block in gather kernels
#define GROUP 16    // lanes per node group

// ---------- CSR build ----------
__global__ void hist_kernel(const int* __restrict__ dst, int* __restrict__ deg) {
    int e = blockIdx.x * blockDim.x + threadIdx.x;
    if (e >= N_EDGES) return;
    atomicAdd(&deg[dst[e]], 1);
}

__global__ void bump_kernel(const int* __restrict__ deg,
                            int* __restrict__ rowstart,
                            int* __restrict__ wp,
                            int* __restrict__ cursor,
                            const int* __restrict__ batch,
                            float* __restrict__ counts) {
    int i = blockIdx.x * blockDim.x + threadIdx.x;
    if (i >= N_NODES) return;
    int d = deg[i];
    int s = atomicAdd(cursor, d);
    rowstart[i] = s;
    wp[i] = s;
    atomicAdd(&counts[batch[i]], 1.0f);
}

__global__ void fill_kernel(const int* __restrict__ src,
                            const int* __restrict__ dst,
                            int* __restrict__ wp,
                            int* __restrict__ ecol) {
    int e = blockIdx.x * blockDim.x + threadIdx.x;
    if (e >= N_EDGES) return;
    int p = atomicAdd(&wp[dst[e]], 1);
    ecol[p] = src[e];
}

// ---------- y = x @ w1_1  (pre-apply layer-1 first matmul; aggregation is linear) ----------
__global__ void xform_kernel(const float* __restrict__ x,
                             const float* __restrict__ w1,   // [16][10]
                             float* __restrict__ y) {        // [N][10]
    int i = blockIdx.x * blockDim.x + threadIdx.x;
    if (i >= N_NODES) return;
    float xi[NFEAT];
    const float4* xr = reinterpret_cast<const float4*>(x + (size_t)i * NFEAT);
#pragma unroll
    for (int q = 0; q < 4; q++) {
        float4 v = xr[q];
        xi[q * 4 + 0] = v.x; xi[q * 4 + 1] = v.y; xi[q * 4 + 2] = v.z; xi[q * 4 + 3] = v.w;
    }
#pragma unroll
    for (int j = 0; j < DIM; j++) {
        float s = 0.f;
#pragma unroll
        for (int f = 0; f < NFEAT; f++) s += xi[f] * w1[f * DIM + j];
        y[(size_t)i * DIM + j] = s;
    }
}

// ---------- fused gather + MLP + pool ----------
// FIRST=true: hin is y = x@w1 (so first matmul is skipped; t = relu(agg + b1)).
// FIRST=false: t = relu((h_i + agg)@w1 + b1). Both: h' = relu(relu-part@w2+b2), relu outer.
template <bool FIRST>
__global__ void gin_gather(const float* __restrict__ hin,
                           const int* __restrict__ rowstart,
                           const int* __restrict__ rowend,   // wp after fill == segment end
                           const int* __restrict__ ecol,
                           const float* __restrict__ w1, const float* __restrict__ b1,
                           const float* __restrict__ w2, const float* __restrict__ b2,
                           const int* __restrict__ batch,
                           float* __restrict__ hout,
                           float* __restrict__ pooled) {
    __shared__ float hp[NPB][DIM];
    __shared__ int gid[NPB];
    int tid = threadIdx.x;
    int grp = tid >> 4;            // 0..15
    int j = tid & 15;              // lane within group
    int lane = tid & 63;
    int base = lane & 48;          // group base within wave
    int i = blockIdx.x * NPB + grp;   // grid sized exactly: i < N_NODES

    int r0 = rowstart[i];
    int r1 = rowend[i];
    float acc = (j < DIM) ? hin[i * DIM + j] : 0.f;

    for (int e0 = r0; e0 < r1; e0 += GROUP) {
        int idx = e0 + j;
        int sv = (idx < r1) ? ecol[idx] : 0;
        int cnt = r1 - e0;
        if (cnt > GROUP) cnt = GROUP;
        for (int k = 0; k < cnt; ++k) {
            int s = __shfl(sv, base + k, 64);
            if (j < DIM) acc += hin[s * DIM + j];
        }
    }

    float t;
    if (FIRST) {
        t = (j < DIM) ? (acc + b1[j]) : 0.f;
        t = t > 0.f ? t : 0.f;
    } else {
        float s1 = (j < DIM) ? b1[j] : 0.f;
#pragma unroll
        for (int f = 0; f < DIM; ++f) {
            float zf = __shfl(acc, base + f, 64);
            if (j < DIM) s1 += zf * w1[f * DIM + j];
        }
        t = s1 > 0.f ? s1 : 0.f;
    }

    float s2 = (j < DIM) ? b2[j] : 0.f;
#pragma unroll
    for (int f = 0; f < DIM; ++f) {
        float tf = __shfl(t, base + f, 64);
        if (j < DIM) s2 += tf * w2[f * DIM + j];
    }
    float hv = s2 > 0.f ? s2 : 0.f;

    if (j < DIM) {
        hout[i * DIM + j] = hv;
        hp[grp][j] = hv;
    }
    if (j == 0) gid[grp] = batch[i];
    __syncthreads();

    // run-length block reduction of the graph-pool (batch is sorted -> few runs)
    if (tid < DIM) {
        int cg = gid[0];
        float s = hp[0][tid];
        for (int n = 1; n < NPB; ++n) {
            int g = gid[n];
            if (g == cg) {
                s += hp[n][tid];
            } else {
                atomicAdd(&pooled[cg * DIM + tid], s);
                cg = g;
                s = hp[n][tid];
            }
        }
        atomicAdd(&pooled[cg * DIM + tid], s);
    }
}

// ---------- readout ----------
__global__ void final_kernel(const float* __restrict__ pooled,  // [5][G][10]
                             const float* __restrict__ counts,  // [G]
                             const float* __restrict__ lw,      // [5][10]
                             float* __restrict__ out) {
    int g = blockIdx.x * blockDim.x + threadIdx.x;
    if (g >= NGRAPH) return;
    float c = counts[g];
    float inv = 1.0f / (c > 1.0f ? c : 1.0f);
    float s = 0.f;
#pragma unroll
    for (int l = 0; l < 5; l++) {
        float d = 0.f;
#pragma unroll
        for (int j = 0; j < DIM; j++)
            d += pooled[(size_t)l * NGRAPH * DIM + (size_t)g * DIM + j] * lw[l * DIM + j];
        s += d * inv;
    }
    out[g] = 1.0f / (1.0f + expf(-s));
}

extern "C" void kernel_launch(void* const* d_in, const int* in_sizes, int n_in,
                              void* d_out, int out_size, void* d_ws, size_t ws_size,
                              hipStream_t stream) {
    const float* x    = (const float*)d_in[0];
    const int*   ei   = (const int*)d_in[1];
    const int*   batch= (const int*)d_in[2];
    const float* w1_1 = (const float*)d_in[3];
    const float* b1_1 = (const float*)d_in[4];
    const float* w2_1 = (const float*)d_in[5];
    const float* b2_1 = (const float*)d_in[6];
    const float* ws1  = (const float*)d_in[7];   // [4][10][10]
    const float* bs1  = (const float*)d_in[8];   // [4][10]
    const float* ws2  = (const float*)d_in[9];   // [4][10][10]
    const float* bs2  = (const float*)d_in[10];  // [4][10]
    const float* lw   = (const float*)d_in[11];  // [5][10]
    float* out = (float*)d_out;

    const int* src = ei;
    const int* dst = ei + N_EDGES;

    // ---- workspace layout ----
    int* deg      = (int*)d_ws;                  // [N]
    int* rowstart = deg + N_NODES;               // [N]
    int* wp       = rowstart + N_NODES;          // [N]
    int* cursor   = wp + N_NODES;                // [4] (1 used)
    int* ecol     = cursor + 4;                  // [E]
    float* ybuf   = (float*)(ecol + N_EDGES);    // [N][10]  (ping)
    float* hbuf   = ybuf + (size_t)N_NODES * DIM;// [N][10]  (pong)
    float* pooled = hbuf + (size_t)N_NODES * DIM;// [5][G][10]
    float* counts = pooled + (size_t)5 * NGRAPH * DIM; // [G]
    size_t needed = (size_t)((char*)(counts + NGRAPH) - (char*)d_ws);
    if (needed > ws_size) return;  // refuse to scribble OOB (will fail validation loudly)

    const int TB = 256;
    int eblocks = (N_EDGES + TB - 1) / TB;
    int nblocks = (N_NODES + TB - 1) / TB;
    int gatherblocks = N_NODES / NPB;            // 12500, exact
    int gblocks = (NGRAPH + TB - 1) / TB;

    // zero accumulators (poisoned workspace must be re-initialized every call)
    hipMemsetAsync(deg, 0, (size_t)N_NODES * sizeof(int), stream);
    hipMemsetAsync(cursor, 0, 4 * sizeof(int), stream);
    hipMemsetAsync(pooled, 0, (size_t)(5 * NGRAPH * DIM + NGRAPH) * sizeof(float), stream);

    // ---- CSR build (unordered segments: no prefix scan needed) ----
    hist_kernel<<<eblocks, TB, 0, stream>>>(dst, deg);
    bump_kernel<<<nblocks, TB, 0, stream>>>(deg, rowstart, wp, cursor, batch, counts);
    fill_kernel<<<eblocks, TB, 0, stream>>>(src, dst, wp, ecol);
    // now: segment of node i = ecol[rowstart[i] .. wp[i])

    // ---- layer 1: pre-apply w1, aggregate in 10-dim ----
    xform_kernel<<<nblocks, TB, 0, stream>>>(x, w1_1, ybuf);
    gin_gather<true><<<gatherblocks, TB, 0, stream>>>(
        ybuf, rowstart, wp, ecol, nullptr, b1_1, w2_1, b2_1, batch,
        hbuf, pooled);

    // ---- layers 2..5 (ping-pong hbuf <-> ybuf) ----
    float* hin = hbuf;
    float* hout = ybuf;
    for (int l = 0; l < 4; l++) {
        gin_gather<false><<<gatherblocks, TB, 0, stream>>>(
            hin, rowstart, wp, ecol,
            ws1 + (size_t)l * DIM * DIM, bs1 + (size_t)l * DIM,
            ws2 + (size_t)l * DIM * DIM, bs2 + (size_t)l * DIM,
            batch, hout, pooled + (size_t)(l + 1) * NGRAPH * DIM);
        float* tmp = hin; hin = hout; hout = tmp;
    }

    // ---- readout ----
    final_kernel<<<gblocks, TB, 0, stream>>>(pooled, counts, lw, out);
}